// Round 1
// baseline (575.736 us; speedup 1.0000x reference)
//
#include <hip/hip_runtime.h>

#define D 2048
#define R 64
#define TOK 16          // tokens per block
#define NTOK 16384
#define HS_STRIDE (D + 8)   // bf16 elements; +8 (16B) pad => rows offset 4 banks

__device__ inline unsigned short f2bf(float f) {
    union { float f; unsigned int u; } c; c.f = f;
    unsigned int u = c.u;
    unsigned int r = (u + 0x7fffu + ((u >> 16) & 1u)) >> 16;  // RNE
    return (unsigned short)r;
}
__device__ inline float bf2f(unsigned short h) {
    union { unsigned int u; float f; } c; c.u = ((unsigned int)h) << 16;
    return c.f;
}

__global__ __launch_bounds__(256, 2)
void adapter_fused(const float* __restrict__ x,
                   const float* __restrict__ gamma,
                   const float* __restrict__ beta,
                   const float* __restrict__ wd,      // (R, D) row-major
                   const float* __restrict__ bd,      // (R)
                   const float* __restrict__ wu,      // (D, R) row-major
                   const float* __restrict__ bu,      // (D)
                   const float* __restrict__ scale_p, // (1)
                   float* __restrict__ out)
{
    __shared__ unsigned short hs[TOK][HS_STRIDE];  // h in bf16
    __shared__ float down_s[TOK][R];

    const int tid  = threadIdx.x;
    const int lane = tid & 63;
    const int wave = tid >> 6;
    const int tok0 = blockIdx.x * TOK;

    // ---------------- Phase 1: LayerNorm (4 tokens per wave) ----------------
    // lane owns d-positions: 4*(lane+64*i)..+3  for i=0..7
    float4 g4[8], b4[8];
    {
        const float4* gamma4 = (const float4*)gamma;
        const float4* beta4  = (const float4*)beta;
        #pragma unroll
        for (int i = 0; i < 8; ++i) {
            g4[i] = gamma4[lane + 64*i];
            b4[i] = beta4[lane + 64*i];
        }
    }
    for (int j = 0; j < 4; ++j) {
        const int m = wave*4 + j;
        const float4* xr = (const float4*)(x + (size_t)(tok0 + m) * D);
        float4 v[8];
        float s = 0.f, ss = 0.f;
        #pragma unroll
        for (int i = 0; i < 8; ++i) {
            v[i] = xr[lane + 64*i];
            s  += (v[i].x + v[i].y) + (v[i].z + v[i].w);
            ss += (v[i].x*v[i].x + v[i].y*v[i].y) + (v[i].z*v[i].z + v[i].w*v[i].w);
        }
        #pragma unroll
        for (int off = 32; off >= 1; off >>= 1) {
            s  += __shfl_xor(s,  off, 64);
            ss += __shfl_xor(ss, off, 64);
        }
        const float mu   = s * (1.0f / D);
        const float var  = ss * (1.0f / D) - mu * mu;
        const float rstd = rsqrtf(var + 1e-5f);
        ushort4* hrow = (ushort4*)(&hs[m][0]);
        #pragma unroll
        for (int i = 0; i < 8; ++i) {
            float h0 = (v[i].x - mu) * rstd * g4[i].x + b4[i].x;
            float h1 = (v[i].y - mu) * rstd * g4[i].y + b4[i].y;
            float h2 = (v[i].z - mu) * rstd * g4[i].z + b4[i].z;
            float h3 = (v[i].w - mu) * rstd * g4[i].w + b4[i].w;
            ushort4 hp;
            hp.x = f2bf(h0); hp.y = f2bf(h1); hp.z = f2bf(h2); hp.w = f2bf(h3);
            hrow[lane + 64*i] = hp;
        }
    }
    __syncthreads();

    // ---------------- Phase 2: down-proj (M=16, N=64, K=2048) ----------------
    // thread = (token m = tid&15, r-quad rg = tid>>4); full-K fp32 accumulate
    {
        const int m  = tid & 15;
        const int rg = tid >> 4;     // 0..15
        const int r0 = rg * 4;
        const ushort4* hrow = (const ushort4*)(&hs[m][0]);
        const float4* w0 = (const float4*)(wd + (size_t)(r0+0) * D);
        const float4* w1 = (const float4*)(wd + (size_t)(r0+1) * D);
        const float4* w2 = (const float4*)(wd + (size_t)(r0+2) * D);
        const float4* w3 = (const float4*)(wd + (size_t)(r0+3) * D);
        float acc0 = 0.f, acc1 = 0.f, acc2 = 0.f, acc3 = 0.f;
        #pragma unroll 4
        for (int k = 0; k < D/4; ++k) {
            ushort4 hu = hrow[k];
            float h0 = bf2f(hu.x), h1 = bf2f(hu.y), h2 = bf2f(hu.z), h3 = bf2f(hu.w);
            float4 a = w0[k]; acc0 += h0*a.x + h1*a.y + h2*a.z + h3*a.w;
            float4 b = w1[k]; acc1 += h0*b.x + h1*b.y + h2*b.z + h3*b.w;
            float4 c = w2[k]; acc2 += h0*c.x + h1*c.y + h2*c.z + h3*c.w;
            float4 d = w3[k]; acc3 += h0*d.x + h1*d.y + h2*d.z + h3*d.w;
        }
        float4 dn;
        dn.x = fmaxf(acc0 + bd[r0+0], 0.f);
        dn.y = fmaxf(acc1 + bd[r0+1], 0.f);
        dn.z = fmaxf(acc2 + bd[r0+2], 0.f);
        dn.w = fmaxf(acc3 + bd[r0+3], 0.f);
        *(float4*)&down_s[m][r0] = dn;
    }
    __syncthreads();

    // ---------------- Phase 3: up-proj + scale + residual ----------------
    // thread owns d-quads g = tid and tid+256 (d = 4g..4g+3); 8-token halves
    const float scl = scale_p[0];
    #pragma unroll
    for (int gi = 0; gi < 2; ++gi) {
        const int g = tid + gi * 256;   // float4 index into D
        const float4* wr0 = (const float4*)(wu + (size_t)(4*g+0) * R);
        const float4* wr1 = (const float4*)(wu + (size_t)(4*g+1) * R);
        const float4* wr2 = (const float4*)(wu + (size_t)(4*g+2) * R);
        const float4* wr3 = (const float4*)(wu + (size_t)(4*g+3) * R);
        const float4 bup = ((const float4*)bu)[g];
        #pragma unroll
        for (int mh = 0; mh < 2; ++mh) {
            float4 acc[8];
            #pragma unroll
            for (int m = 0; m < 8; ++m) acc[m] = make_float4(0.f, 0.f, 0.f, 0.f);
            #pragma unroll 4
            for (int c = 0; c < R/4; ++c) {   // r-chunk of 4
                const float4 W0 = wr0[c];
                const float4 W1 = wr1[c];
                const float4 W2 = wr2[c];
                const float4 W3 = wr3[c];
                #pragma unroll
                for (int m = 0; m < 8; ++m) {
                    const float4 dv = *(const float4*)&down_s[mh*8 + m][c*4];
                    acc[m].x += W0.x*dv.x + W0.y*dv.y + W0.z*dv.z + W0.w*dv.w;
                    acc[m].y += W1.x*dv.x + W1.y*dv.y + W1.z*dv.z + W1.w*dv.w;
                    acc[m].z += W2.x*dv.x + W2.y*dv.y + W2.z*dv.z + W2.w*dv.w;
                    acc[m].w += W3.x*dv.x + W3.y*dv.y + W3.z*dv.z + W3.w*dv.w;
                }
            }
            #pragma unroll
            for (int m = 0; m < 8; ++m) {
                const int mm = mh*8 + m;
                const size_t row = (size_t)(tok0 + mm) * D;
                const float4 xv = ((const float4*)(x + row))[g];
                float4 o;
                o.x = scl * (acc[m].x + bup.x) + xv.x;
                o.y = scl * (acc[m].y + bup.y) + xv.y;
                o.z = scl * (acc[m].z + bup.z) + xv.z;
                o.w = scl * (acc[m].w + bup.w) + xv.w;
                ((float4*)(out + row))[g] = o;
            }
        }
    }
}

extern "C" void kernel_launch(void* const* d_in, const int* in_sizes, int n_in,
                              void* d_out, int out_size, void* d_ws, size_t ws_size,
                              hipStream_t stream) {
    const float* x     = (const float*)d_in[0];
    const float* gamma = (const float*)d_in[1];
    const float* beta  = (const float*)d_in[2];
    const float* wd    = (const float*)d_in[3];
    const float* bd    = (const float*)d_in[4];
    const float* wu    = (const float*)d_in[5];
    const float* bu    = (const float*)d_in[6];
    const float* scl   = (const float*)d_in[7];
    float* out = (float*)d_out;
    adapter_fused<<<NTOK / TOK, 256, 0, stream>>>(x, gamma, beta, wd, bd, wu, bu, scl, out);
}

// Round 2
// 428.408 us; speedup vs baseline: 1.3439x; 1.3439x over previous
//
#include <hip/hip_runtime.h>

#define D 2048
#define R 64
#define NTOK 16384
#define KT 256                  // k-tile (floats)
#define NKT (D / KT)            // 8
#define HROW (KT + 8)           // h row stride in bf16 (+16B pad -> 2-way banks only)
#define TROW 80                 // down_t row stride in bf16 (64 + 16; 160B, 16B-aligned)

typedef float  f32x4  __attribute__((ext_vector_type(4)));
typedef short  s16x8  __attribute__((ext_vector_type(8)));

__device__ inline unsigned short f2bf(float f) {
    union { float f; unsigned int u; } c; c.f = f;
    unsigned int u = c.u;
    return (unsigned short)((u + 0x7fffu + ((u >> 16) & 1u)) >> 16);  // RNE
}

// ---- weight pre-conversion: fp32 -> bf16 into workspace ----
__global__ __launch_bounds__(256)
void convert_w(const float* __restrict__ wd, const float* __restrict__ wu,
               unsigned short* __restrict__ wdb, unsigned short* __restrict__ wub) {
    const int i = blockIdx.x * 256 + threadIdx.x;      // float4 index, 32768 total
    const float4 a = ((const float4*)wd)[i];
    const float4 b = ((const float4*)wu)[i];
    ushort4 pa, pb;
    pa.x = f2bf(a.x); pa.y = f2bf(a.y); pa.z = f2bf(a.z); pa.w = f2bf(a.w);
    pb.x = f2bf(b.x); pb.y = f2bf(b.y); pb.z = f2bf(b.z); pb.w = f2bf(b.w);
    ((ushort4*)wdb)[i] = pa;
    ((ushort4*)wub)[i] = pb;
}

// ---- fused adapter: one wave per 16 tokens, no barriers ----
__global__ __launch_bounds__(64, 4)
void adapter_mfma(const float* __restrict__ x,
                  const float* __restrict__ gamma,
                  const float* __restrict__ beta,
                  const unsigned short* __restrict__ wdb,   // (R, D) bf16
                  const float* __restrict__ bd,
                  const unsigned short* __restrict__ wub,   // (D, R) bf16
                  const float* __restrict__ bu,
                  const float* __restrict__ scale_p,
                  float* __restrict__ out)
{
    __shared__ __align__(16) unsigned short h_lds[16 * HROW];   // 8448 B; reused as down_t

    const int lane = threadIdx.x;        // 0..63 (one wave per block)
    const int l15  = lane & 15;
    const int quad = lane >> 4;          // 0..3
    const int tok0 = blockIdx.x * 16;

    // ---------------- stats pass: mean / rstd per token ----------------
    float muv[16], rsv[16];
    #pragma unroll
    for (int m = 0; m < 16; ++m) {
        const float4* xr = (const float4*)(x + (size_t)(tok0 + m) * D);
        float s = 0.f, ss = 0.f;
        #pragma unroll
        for (int i = 0; i < 8; ++i) {
            float4 v = xr[lane + 64 * i];
            s  += (v.x + v.y) + (v.z + v.w);
            ss += (v.x * v.x + v.y * v.y) + (v.z * v.z + v.w * v.w);
        }
        #pragma unroll
        for (int off = 32; off >= 1; off >>= 1) {
            s  += __shfl_xor(s,  off, 64);
            ss += __shfl_xor(ss, off, 64);
        }
        const float mu = s * (1.0f / D);
        muv[m] = mu;
        rsv[m] = rsqrtf(ss * (1.0f / D) - mu * mu + 1e-5f);
    }

    // ---------------- down-proj: D[16 m][64 r], K-tiled ----------------
    f32x4 acc[4];
    #pragma unroll
    for (int nt = 0; nt < 4; ++nt) acc[nt] = (f32x4){0.f, 0.f, 0.f, 0.f};

    for (int kt = 0; kt < NKT; ++kt) {
        // gamma/beta slice for this k-tile: one float4 per lane
        const float4 g4 = ((const float4*)gamma)[kt * (KT / 4) + lane];
        const float4 b4 = ((const float4*)beta )[kt * (KT / 4) + lane];
        // produce h tile (coalesced x read, bf16 into LDS)
        #pragma unroll
        for (int m = 0; m < 16; ++m) {
            const float4 v = ((const float4*)(x + (size_t)(tok0 + m) * D + kt * KT))[lane];
            const float mu = muv[m], rs = rsv[m];
            ushort4 hp;
            hp.x = f2bf((v.x - mu) * rs * g4.x + b4.x);
            hp.y = f2bf((v.y - mu) * rs * g4.y + b4.y);
            hp.z = f2bf((v.z - mu) * rs * g4.z + b4.z);
            hp.w = f2bf((v.w - mu) * rs * g4.w + b4.w);
            *(ushort4*)&h_lds[m * HROW + lane * 4] = hp;
        }
        // MFMA over this k-tile
        #pragma unroll
        for (int s = 0; s < KT / 32; ++s) {
            const s16x8 a = *(const s16x8*)&h_lds[l15 * HROW + s * 32 + quad * 8];
            const int kg = kt * KT + s * 32 + quad * 8;
            #pragma unroll
            for (int nt = 0; nt < 4; ++nt) {
                const s16x8 b = *(const s16x8*)&wdb[(size_t)(nt * 16 + l15) * D + kg];
                acc[nt] = __builtin_amdgcn_mfma_f32_16x16x32_bf16(a, b, acc[nt], 0, 0, 0);
            }
        }
    }

    // ---------------- bias + ReLU, transpose C-layout -> A-layout ----------------
    unsigned short* down_t = h_lds;   // reuse (h no longer needed)
    #pragma unroll
    for (int nt = 0; nt < 4; ++nt) {
        const int r = nt * 16 + l15;
        const float bdv = bd[r];
        #pragma unroll
        for (int reg = 0; reg < 4; ++reg) {
            const int m = quad * 4 + reg;
            const float dv = fmaxf(acc[nt][reg] + bdv, 0.f);
            down_t[m * TROW + r] = f2bf(dv);
        }
    }
    // A-frags for up-proj (K = 64 = 2 MFMA steps)
    const s16x8 a0 = *(const s16x8*)&down_t[l15 * TROW + quad * 8];
    const s16x8 a1 = *(const s16x8*)&down_t[l15 * TROW + 32 + quad * 8];

    // ---------------- up-proj + scale + residual ----------------
    const float scl = scale_p[0];
    #pragma unroll 2
    for (int nt2 = 0; nt2 < D / 16; ++nt2) {
        const int dd = nt2 * 16 + l15;
        const s16x8 b0 = *(const s16x8*)&wub[(size_t)dd * R + quad * 8];
        const s16x8 b1 = *(const s16x8*)&wub[(size_t)dd * R + 32 + quad * 8];
        f32x4 c = (f32x4){0.f, 0.f, 0.f, 0.f};
        c = __builtin_amdgcn_mfma_f32_16x16x32_bf16(a0, b0, c, 0, 0, 0);
        c = __builtin_amdgcn_mfma_f32_16x16x32_bf16(a1, b1, c, 0, 0, 0);
        const float bun = bu[dd];
        #pragma unroll
        for (int reg = 0; reg < 4; ++reg) {
            const int m = quad * 4 + reg;
            const size_t idx = (size_t)(tok0 + m) * D + dd;
            out[idx] = scl * (c[reg] + bun) + x[idx];
        }
    }
}

extern "C" void kernel_launch(void* const* d_in, const int* in_sizes, int n_in,
                              void* d_out, int out_size, void* d_ws, size_t ws_size,
                              hipStream_t stream) {
    const float* x     = (const float*)d_in[0];
    const float* gamma = (const float*)d_in[1];
    const float* beta  = (const float*)d_in[2];
    const float* wd    = (const float*)d_in[3];
    const float* bd    = (const float*)d_in[4];
    const float* wu    = (const float*)d_in[5];
    const float* bu    = (const float*)d_in[6];
    const float* scl   = (const float*)d_in[7];
    float* out = (float*)d_out;

    unsigned short* wdb = (unsigned short*)d_ws;                     // 131072 bf16
    unsigned short* wub = wdb + (size_t)R * D;                       // 131072 bf16

    convert_w<<<(R * D / 4) / 256, 256, 0, stream>>>(wd, wu, wdb, wub);
    adapter_mfma<<<NTOK / 16, 64, 0, stream>>>(x, gamma, beta, wdb, bd, wub, bu, scl, out);
}

// Round 3
// 358.871 us; speedup vs baseline: 1.6043x; 1.1938x over previous
//
#include <hip/hip_runtime.h>

#define D 2048
#define R 64
#define NTOK 16384
#define KT 256              // k-tile per iteration (floats)
#define KW 512              // K slice per wave (2 tiles)
#define HROW 264            // h row stride in bf16 (256 + 8 -> pad)
#define PROW 68             // P partial row stride in fp32 (64 + 4 -> pad)
#define WREG 8448           // per-wave LDS region bytes (16*HROW*2)

typedef float f32x4 __attribute__((ext_vector_type(4)));
typedef short s16x8 __attribute__((ext_vector_type(8)));

__device__ inline unsigned short f2bf(float f) {
    union { float f; unsigned int u; } c; c.f = f;
    unsigned int u = c.u;
    return (unsigned short)((u + 0x7fffu + ((u >> 16) & 1u)) >> 16);  // RNE
}

// ---- prep 1: wd, wu fp32 -> bf16 ----
__global__ __launch_bounds__(256)
void convert_w(const float* __restrict__ wd, const float* __restrict__ wu,
               unsigned short* __restrict__ wdb, unsigned short* __restrict__ wub) {
    const int i = blockIdx.x * 256 + threadIdx.x;      // 32768 float4 per array
    const float4 a = ((const float4*)wd)[i];
    const float4 b = ((const float4*)wu)[i];
    ushort4 pa, pb;
    pa.x = f2bf(a.x); pa.y = f2bf(a.y); pa.z = f2bf(a.z); pa.w = f2bf(a.w);
    pb.x = f2bf(b.x); pb.y = f2bf(b.y); pb.z = f2bf(b.z); pb.w = f2bf(b.w);
    ((ushort4*)wdb)[i] = pa;
    ((ushort4*)wub)[i] = pb;
}

// ---- prep 2: u[r] = wd[r,:]·gamma ; cb[r] = wd[r,:]·beta + bd[r] ----
__global__ __launch_bounds__(256)
void prep_uc(const float* __restrict__ wd, const float* __restrict__ gamma,
             const float* __restrict__ beta, const float* __restrict__ bd,
             float* __restrict__ u, float* __restrict__ cb) {
    const int r = blockIdx.x;
    const int tid = threadIdx.x;
    const int lane = tid & 63, wave = tid >> 6;
    float su = 0.f, sc = 0.f;
    for (int i = tid; i < D / 4; i += 256) {
        const float4 w  = ((const float4*)(wd + (size_t)r * D))[i];
        const float4 g  = ((const float4*)gamma)[i];
        const float4 be = ((const float4*)beta)[i];
        su += w.x * g.x + w.y * g.y + w.z * g.z + w.w * g.w;
        sc += w.x * be.x + w.y * be.y + w.z * be.z + w.w * be.w;
    }
    #pragma unroll
    for (int off = 32; off >= 1; off >>= 1) {
        su += __shfl_xor(su, off, 64);
        sc += __shfl_xor(sc, off, 64);
    }
    __shared__ float red[2][4];
    if (lane == 0) { red[0][wave] = su; red[1][wave] = sc; }
    __syncthreads();
    if (tid == 0) {
        u[r]  = red[0][0] + red[0][1] + red[0][2] + red[0][3];
        cb[r] = red[1][0] + red[1][1] + red[1][2] + red[1][3] + bd[r];
    }
}

// ---- fused adapter: 256 threads, 4 waves K/N-split over 16 tokens ----
__global__ __launch_bounds__(256, 4)
void adapter_mfma(const float* __restrict__ x,
                  const float* __restrict__ gamma,
                  const unsigned short* __restrict__ wdb,   // (R, D) bf16
                  const unsigned short* __restrict__ wub,   // (D, R) bf16
                  const float* __restrict__ u,
                  const float* __restrict__ cb,
                  const float* __restrict__ bu,
                  const float* __restrict__ scale_p,
                  float* __restrict__ out)
{
    __shared__ __align__(16) unsigned char smem[4][WREG];   // h (bf16) then P partial (fp32)
    __shared__ float s_lds[4][16];
    __shared__ float ss_lds[4][16];

    const int tid  = threadIdx.x;
    const int wave = tid >> 6;
    const int lane = tid & 63;
    const int l15  = lane & 15;
    const int quad = lane >> 4;
    const int tok0 = blockIdx.x * 16;

    unsigned short* h = (unsigned short*)smem[wave];
    float*          pw = (float*)smem[wave];

    float sm[16], ssm[16];
    #pragma unroll
    for (int m = 0; m < 16; ++m) { sm[m] = 0.f; ssm[m] = 0.f; }

    f32x4 acc[4];
    #pragma unroll
    for (int nt = 0; nt < 4; ++nt) acc[nt] = (f32x4){0.f, 0.f, 0.f, 0.f};

    // ---- single pass over this wave's K slice: stats + gamma*x (bf16) + MFMA ----
    const int kbase = wave * KW;
    #pragma unroll
    for (int kt = 0; kt < KW / KT; ++kt) {
        const int kb = kbase + kt * KT;
        const float4 g4 = ((const float4*)gamma)[(kb >> 2) + lane];
        #pragma unroll
        for (int m = 0; m < 16; ++m) {
            const float4 v = ((const float4*)(x + (size_t)(tok0 + m) * D + kb))[lane];
            sm[m]  += (v.x + v.y) + (v.z + v.w);
            ssm[m] += (v.x * v.x + v.y * v.y) + (v.z * v.z + v.w * v.w);
            ushort4 hp;
            hp.x = f2bf(v.x * g4.x);
            hp.y = f2bf(v.y * g4.y);
            hp.z = f2bf(v.z * g4.z);
            hp.w = f2bf(v.w * g4.w);
            *(ushort4*)&h[m * HROW + lane * 4] = hp;
        }
        #pragma unroll
        for (int s = 0; s < KT / 32; ++s) {
            const s16x8 a = *(const s16x8*)&h[l15 * HROW + s * 32 + quad * 8];
            const int kg = kb + s * 32 + quad * 8;
            #pragma unroll
            for (int nt = 0; nt < 4; ++nt) {
                const s16x8 b = *(const s16x8*)&wdb[(size_t)(nt * 16 + l15) * D + kg];
                acc[nt] = __builtin_amdgcn_mfma_f32_16x16x32_bf16(a, b, acc[nt], 0, 0, 0);
            }
        }
    }

    // ---- reduce per-token stats within wave, publish partials ----
    #pragma unroll
    for (int m = 0; m < 16; ++m) {
        float s = sm[m], q = ssm[m];
        #pragma unroll
        for (int off = 32; off >= 1; off >>= 1) {
            s += __shfl_xor(s, off, 64);
            q += __shfl_xor(q, off, 64);
        }
        sm[m] = s; ssm[m] = q;
    }
    if (lane == 0) {
        #pragma unroll
        for (int m = 0; m < 16; ++m) { s_lds[wave][m] = sm[m]; ss_lds[wave][m] = ssm[m]; }
    }

    // ---- publish P partial (overwrites own h region; DS ops are in-order per wave) ----
    #pragma unroll
    for (int nt = 0; nt < 4; ++nt)
        #pragma unroll
        for (int reg = 0; reg < 4; ++reg)
            pw[(quad * 4 + reg) * PROW + nt * 16 + l15] = acc[nt][reg];

    __syncthreads();

    // ---- finalize stats for token m = l15 ----
    const float s_tot  = s_lds[0][l15] + s_lds[1][l15] + s_lds[2][l15] + s_lds[3][l15];
    const float ss_tot = ss_lds[0][l15] + ss_lds[1][l15] + ss_lds[2][l15] + ss_lds[3][l15];
    const float mu = s_tot * (1.0f / D);
    const float rs = rsqrtf(ss_tot * (1.0f / D) - mu * mu + 1e-5f);

    // ---- build up-proj A-frags: down[m=l15][k=r] = relu(rs*(P - mu*u) + cb) ----
    s16x8 afrag[2];
    #pragma unroll
    for (int f = 0; f < 2; ++f) {
        const int rb = f * 32 + quad * 8;
        float ps[8];
        #pragma unroll
        for (int e = 0; e < 8; ++e) ps[e] = 0.f;
        #pragma unroll
        for (int w = 0; w < 4; ++w) {
            const float* pv = (const float*)smem[w];
            const f32x4 pA = *(const f32x4*)&pv[l15 * PROW + rb];
            const f32x4 pB = *(const f32x4*)&pv[l15 * PROW + rb + 4];
            ps[0] += pA[0]; ps[1] += pA[1]; ps[2] += pA[2]; ps[3] += pA[3];
            ps[4] += pB[0]; ps[5] += pB[1]; ps[6] += pB[2]; ps[7] += pB[3];
        }
        const f32x4 u0 = *(const f32x4*)&u[rb];
        const f32x4 u1 = *(const f32x4*)&u[rb + 4];
        const f32x4 c0 = *(const f32x4*)&cb[rb];
        const f32x4 c1 = *(const f32x4*)&cb[rb + 4];
        s16x8 af;
        #pragma unroll
        for (int e = 0; e < 4; ++e) {
            const float v0 = fmaxf(rs * (ps[e]     - mu * u0[e]) + c0[e], 0.f);
            const float v1 = fmaxf(rs * (ps[4 + e] - mu * u1[e]) + c1[e], 0.f);
            af[e]     = (short)f2bf(v0);
            af[4 + e] = (short)f2bf(v1);
        }
        afrag[f] = af;
    }

    // ---- up-proj + scale + residual: wave handles d in [wave*512, wave*512+512) ----
    const float scl = scale_p[0];
    const int nbase = wave * 512;
    #pragma unroll 4
    for (int t = 0; t < 32; ++t) {
        const int dd = nbase + t * 16 + l15;
        const s16x8 b0 = *(const s16x8*)&wub[(size_t)dd * R + quad * 8];
        const s16x8 b1 = *(const s16x8*)&wub[(size_t)dd * R + 32 + quad * 8];
        f32x4 c = (f32x4){0.f, 0.f, 0.f, 0.f};
        c = __builtin_amdgcn_mfma_f32_16x16x32_bf16(afrag[0], b0, c, 0, 0, 0);
        c = __builtin_amdgcn_mfma_f32_16x16x32_bf16(afrag[1], b1, c, 0, 0, 0);
        const float bun = bu[dd];
        #pragma unroll
        for (int reg = 0; reg < 4; ++reg) {
            const int m = quad * 4 + reg;
            const size_t idx = (size_t)(tok0 + m) * D + dd;
            out[idx] = scl * (c[reg] + bun) + x[idx];
        }
    }
}

extern "C" void kernel_launch(void* const* d_in, const int* in_sizes, int n_in,
                              void* d_out, int out_size, void* d_ws, size_t ws_size,
                              hipStream_t stream) {
    const float* x     = (const float*)d_in[0];
    const float* gamma = (const float*)d_in[1];
    const float* beta  = (const float*)d_in[2];
    const float* wd    = (const float*)d_in[3];
    const float* bd    = (const float*)d_in[4];
    const float* wu    = (const float*)d_in[5];
    const float* bu    = (const float*)d_in[6];
    const float* scl   = (const float*)d_in[7];
    float* out = (float*)d_out;

    unsigned short* wdb = (unsigned short*)d_ws;                 // R*D bf16
    unsigned short* wub = wdb + (size_t)R * D;                   // D*R bf16
    float* u  = (float*)(wub + (size_t)D * R);                   // R fp32
    float* cb = u + R;                                           // R fp32

    convert_w<<<(R * D / 4) / 256, 256, 0, stream>>>(wd, wu, wdb, wub);
    prep_uc<<<R, 256, 0, stream>>>(wd, gamma, beta, bd, u, cb);
    adapter_mfma<<<NTOK / 16, 256, 0, stream>>>(x, gamma, wdb, wub, u, cb, bu, scl, out);
}

// Round 4
// 323.949 us; speedup vs baseline: 1.7772x; 1.1078x over previous
//
#include <hip/hip_runtime.h>

#define D 2048
#define R 64
#define NTOK 16384
#define KT 256              // k-tile per iteration (floats)
#define KW 512              // K slice per wave (2 tiles)
#define HROW 264            // h row stride in bf16 (256 + 8 pad, mult of 8)
#define PROW 68             // P partial row stride in fp32 (64 + 4 pad)
#define SROW 132            // epilogue staging row stride in fp32 (128 + 4 pad)
#define WREG 8448           // per-wave LDS region bytes (= 16*HROW*2 = 16*SROW*4)

typedef float f32x4 __attribute__((ext_vector_type(4)));
typedef short s16x8 __attribute__((ext_vector_type(8)));

__device__ inline unsigned short f2bf(float f) {
    union { float f; unsigned int u; } c; c.f = f;
    unsigned int u = c.u;
    return (unsigned short)((u + 0x7fffu + ((u >> 16) & 1u)) >> 16);  // RNE
}
__device__ inline ushort4 pack4(float4 v) {
    ushort4 p;
    p.x = f2bf(v.x); p.y = f2bf(v.y); p.z = f2bf(v.z); p.w = f2bf(v.w);
    return p;
}

// ---- prep 1: repack wd, wu into bf16 MFMA B-fragment order ----
// wdbp frag f = (ks*4 + nt)*64 + lane : element wd[nt*16 + (lane&15)][ks*32 + (lane>>4)*8 + j]
// wubp frag f = (nt2*2 + s)*64 + lane : element wu[nt2*16 + (lane&15)][s*32 + (lane>>4)*8 + j]
__global__ __launch_bounds__(256)
void convert_pack(const float* __restrict__ wd, const float* __restrict__ wu,
                  unsigned short* __restrict__ wdbp, unsigned short* __restrict__ wubp) {
    const int fid  = blockIdx.x * 256 + threadIdx.x;   // 0..16383
    const int lane = fid & 63;
    const int l15  = lane & 15;
    const int quad = lane >> 4;
    {
        const int nt = (fid >> 6) & 3;
        const int ks = fid >> 8;                       // 0..63
        const int r  = nt * 16 + l15;
        const int k0 = ks * 32 + quad * 8;
        const float4 a0 = *(const float4*)(wd + (size_t)r * D + k0);
        const float4 a1 = *(const float4*)(wd + (size_t)r * D + k0 + 4);
        *(ushort4*)(wdbp + (size_t)fid * 8)     = pack4(a0);
        *(ushort4*)(wdbp + (size_t)fid * 8 + 4) = pack4(a1);
    }
    {
        const int s   = (fid >> 6) & 1;
        const int nt2 = fid >> 7;                      // 0..127
        const int dd  = nt2 * 16 + l15;
        const int r0  = s * 32 + quad * 8;
        const float4 b0 = *(const float4*)(wu + (size_t)dd * R + r0);
        const float4 b1 = *(const float4*)(wu + (size_t)dd * R + r0 + 4);
        *(ushort4*)(wubp + (size_t)fid * 8)     = pack4(b0);
        *(ushort4*)(wubp + (size_t)fid * 8 + 4) = pack4(b1);
    }
}

// ---- prep 2: u[r] = wd[r,:]·gamma ; cb[r] = wd[r,:]·beta + bd[r] ----
__global__ __launch_bounds__(256)
void prep_uc(const float* __restrict__ wd, const float* __restrict__ gamma,
             const float* __restrict__ beta, const float* __restrict__ bd,
             float* __restrict__ u, float* __restrict__ cb) {
    const int r = blockIdx.x;
    const int tid = threadIdx.x;
    const int lane = tid & 63, wave = tid >> 6;
    float su = 0.f, sc = 0.f;
    for (int i = tid; i < D / 4; i += 256) {
        const float4 w  = ((const float4*)(wd + (size_t)r * D))[i];
        const float4 g  = ((const float4*)gamma)[i];
        const float4 be = ((const float4*)beta)[i];
        su += w.x * g.x + w.y * g.y + w.z * g.z + w.w * g.w;
        sc += w.x * be.x + w.y * be.y + w.z * be.z + w.w * be.w;
    }
    #pragma unroll
    for (int off = 32; off >= 1; off >>= 1) {
        su += __shfl_xor(su, off, 64);
        sc += __shfl_xor(sc, off, 64);
    }
    __shared__ float red[2][4];
    if (lane == 0) { red[0][wave] = su; red[1][wave] = sc; }
    __syncthreads();
    if (tid == 0) {
        u[r]  = red[0][0] + red[0][1] + red[0][2] + red[0][3];
        cb[r] = red[1][0] + red[1][1] + red[1][2] + red[1][3] + bd[r];
    }
}

// ---- fused adapter: 256 threads, 4 waves K/N-split over 16 tokens ----
__global__ __launch_bounds__(256, 4)
void adapter_mfma(const float* __restrict__ x,
                  const float* __restrict__ gamma,
                  const unsigned short* __restrict__ wdbp,  // frag-major (R,D) bf16
                  const unsigned short* __restrict__ wubp,  // frag-major (D,R) bf16
                  const float* __restrict__ u,
                  const float* __restrict__ cb,
                  const float* __restrict__ bu,
                  const float* __restrict__ scale_p,
                  float* __restrict__ out)
{
    __shared__ __align__(16) unsigned char smem[4][WREG];   // h (bf16) -> P (fp32) -> staging (fp32)
    __shared__ float s_lds[4][16];
    __shared__ float ss_lds[4][16];

    const int tid  = threadIdx.x;
    const int wave = tid >> 6;
    const int lane = tid & 63;
    const int l15  = lane & 15;
    const int quad = lane >> 4;
    const int tok0 = blockIdx.x * 16;

    unsigned short* h  = (unsigned short*)smem[wave];
    float*          pw = (float*)smem[wave];

    float sm[16], ssm[16];
    #pragma unroll
    for (int m = 0; m < 16; ++m) { sm[m] = 0.f; ssm[m] = 0.f; }

    f32x4 acc[4];
    #pragma unroll
    for (int nt = 0; nt < 4; ++nt) acc[nt] = (f32x4){0.f, 0.f, 0.f, 0.f};

    // ---- single pass over this wave's K slice: stats + gamma*x (bf16) + MFMA ----
    const int kbase = wave * KW;
    #pragma unroll
    for (int kt = 0; kt < KW / KT; ++kt) {
        const int kb = kbase + kt * KT;
        const float4 g4 = ((const float4*)gamma)[(kb >> 2) + lane];
        #pragma unroll
        for (int m = 0; m < 16; ++m) {
            const float4 v = ((const float4*)(x + (size_t)(tok0 + m) * D + kb))[lane];
            sm[m]  += (v.x + v.y) + (v.z + v.w);
            ssm[m] += (v.x * v.x + v.y * v.y) + (v.z * v.z + v.w * v.w);
            float4 hg;
            hg.x = v.x * g4.x; hg.y = v.y * g4.y; hg.z = v.z * g4.z; hg.w = v.w * g4.w;
            *(ushort4*)&h[m * HROW + lane * 4] = pack4(hg);
        }
        const int ks0 = (kb >> 5);
        #pragma unroll
        for (int s = 0; s < KT / 32; ++s) {
            const s16x8 a = *(const s16x8*)&h[l15 * HROW + s * 32 + quad * 8];
            #pragma unroll
            for (int nt = 0; nt < 4; ++nt) {
                const s16x8 b = ((const s16x8*)wdbp)[((ks0 + s) * 4 + nt) * 64 + lane];
                acc[nt] = __builtin_amdgcn_mfma_f32_16x16x32_bf16(a, b, acc[nt], 0, 0, 0);
            }
        }
    }

    // ---- reduce per-token stats within wave, publish partials ----
    #pragma unroll
    for (int m = 0; m < 16; ++m) {
        float s = sm[m], q = ssm[m];
        #pragma unroll
        for (int off = 32; off >= 1; off >>= 1) {
            s += __shfl_xor(s, off, 64);
            q += __shfl_xor(q, off, 64);
        }
        sm[m] = s; ssm[m] = q;
    }
    if (lane == 0) {
        #pragma unroll
        for (int m = 0; m < 16; ++m) { s_lds[wave][m] = sm[m]; ss_lds[wave][m] = ssm[m]; }
    }

    // ---- publish P partial (overwrites own h region; per-wave DS in-order) ----
    #pragma unroll
    for (int nt = 0; nt < 4; ++nt)
        #pragma unroll
        for (int reg = 0; reg < 4; ++reg)
            pw[(quad * 4 + reg) * PROW + nt * 16 + l15] = acc[nt][reg];

    __syncthreads();

    // ---- finalize stats for token m = l15 ----
    const float s_tot  = s_lds[0][l15] + s_lds[1][l15] + s_lds[2][l15] + s_lds[3][l15];
    const float ss_tot = ss_lds[0][l15] + ss_lds[1][l15] + ss_lds[2][l15] + ss_lds[3][l15];
    const float mu = s_tot * (1.0f / D);
    const float rs = rsqrtf(ss_tot * (1.0f / D) - mu * mu + 1e-5f);

    // ---- build up-proj A-frags: down[m=l15][k=r] = relu(rs*(P - mu*u) + cb) ----
    s16x8 afrag[2];
    #pragma unroll
    for (int f = 0; f < 2; ++f) {
        const int rb = f * 32 + quad * 8;
        float ps[8];
        #pragma unroll
        for (int e = 0; e < 8; ++e) ps[e] = 0.f;
        #pragma unroll
        for (int w = 0; w < 4; ++w) {
            const float* pv = (const float*)smem[w];
            const f32x4 pA = *(const f32x4*)&pv[l15 * PROW + rb];
            const f32x4 pB = *(const f32x4*)&pv[l15 * PROW + rb + 4];
            ps[0] += pA[0]; ps[1] += pA[1]; ps[2] += pA[2]; ps[3] += pA[3];
            ps[4] += pB[0]; ps[5] += pB[1]; ps[6] += pB[2]; ps[7] += pB[3];
        }
        const f32x4 u0 = *(const f32x4*)&u[rb];
        const f32x4 u1 = *(const f32x4*)&u[rb + 4];
        const f32x4 c0 = *(const f32x4*)&cb[rb];
        const f32x4 c1 = *(const f32x4*)&cb[rb + 4];
        s16x8 af;
        #pragma unroll
        for (int e = 0; e < 4; ++e) {
            const float v0 = fmaxf(rs * (ps[e]     - mu * u0[e]) + c0[e], 0.f);
            const float v1 = fmaxf(rs * (ps[4 + e] - mu * u1[e]) + c1[e], 0.f);
            af[e]     = (short)f2bf(v0);
            af[4 + e] = (short)f2bf(v1);
        }
        afrag[f] = af;
    }

    __syncthreads();   // all waves done reading P partials before staging reuse

    // ---- up-proj + scale + residual, LDS-staged coalesced epilogue ----
    // wave owns d in [wave*512, wave*512+512), processed as 4 chunks of 128
    const float scl = scale_p[0];
    float* stg = (float*)smem[wave];
    const int nbase = wave * 512;
    #pragma unroll
    for (int c = 0; c < 4; ++c) {
        const int dbase = nbase + c * 128;
        const int nt2_0 = dbase >> 4;
        // compute 8 d-tiles of 16, stage C into LDS [m][dloc]
        #pragma unroll
        for (int t = 0; t < 8; ++t) {
            const s16x8 b0 = ((const s16x8*)wubp)[((nt2_0 + t) * 2 + 0) * 64 + lane];
            const s16x8 b1 = ((const s16x8*)wubp)[((nt2_0 + t) * 2 + 1) * 64 + lane];
            f32x4 cc = (f32x4){0.f, 0.f, 0.f, 0.f};
            cc = __builtin_amdgcn_mfma_f32_16x16x32_bf16(afrag[0], b0, cc, 0, 0, 0);
            cc = __builtin_amdgcn_mfma_f32_16x16x32_bf16(afrag[1], b1, cc, 0, 0, 0);
            #pragma unroll
            for (int reg = 0; reg < 4; ++reg)
                stg[(quad * 4 + reg) * SROW + t * 16 + l15] = cc[reg];
        }
        // write out: per instr 4 rows x 256 B contiguous (full lines, no RMW)
        #pragma unroll
        for (int j = 0; j < 2; ++j) {
            const int dloc = j * 64 + l15 * 4;
            const int dd   = dbase + dloc;
            const float4 bu4 = *(const float4*)(bu + dd);
            #pragma unroll
            for (int mg = 0; mg < 4; ++mg) {
                const int m = mg * 4 + quad;
                const f32x4 v = *(const f32x4*)&stg[m * SROW + dloc];
                const size_t idx = (size_t)(tok0 + m) * D + dd;
                const float4 xv = *(const float4*)(x + idx);
                f32x4 o;
                o[0] = scl * (v[0] + bu4.x) + xv.x;
                o[1] = scl * (v[1] + bu4.y) + xv.y;
                o[2] = scl * (v[2] + bu4.z) + xv.z;
                o[3] = scl * (v[3] + bu4.w) + xv.w;
                __builtin_nontemporal_store(o, (f32x4*)(out + idx));
            }
        }
    }
}

extern "C" void kernel_launch(void* const* d_in, const int* in_sizes, int n_in,
                              void* d_out, int out_size, void* d_ws, size_t ws_size,
                              hipStream_t stream) {
    const float* x     = (const float*)d_in[0];
    const float* gamma = (const float*)d_in[1];
    const float* beta  = (const float*)d_in[2];
    const float* wd    = (const float*)d_in[3];
    const float* bd    = (const float*)d_in[4];
    const float* wu    = (const float*)d_in[5];
    const float* bu    = (const float*)d_in[6];
    const float* scl   = (const float*)d_in[7];
    float* out = (float*)d_out;

    unsigned short* wdbp = (unsigned short*)d_ws;                // R*D bf16, frag-major
    unsigned short* wubp = wdbp + (size_t)R * D;                 // D*R bf16, frag-major
    float* u  = (float*)(wubp + (size_t)D * R);                  // R fp32
    float* cb = u + R;                                           // R fp32

    convert_pack<<<(R * D / 8) / 256, 256, 0, stream>>>(wd, wu, wdbp, wubp);
    prep_uc<<<R, 256, 0, stream>>>(wd, gamma, beta, bd, u, cb);
    adapter_mfma<<<NTOK / 16, 256, 0, stream>>>(x, gamma, wdbp, wubp, u, cb, bu, scl, out);
}